// Round 12
// baseline (248.233 us; speedup 1.0000x reference)
//
#include <hip/hip_runtime.h>
#include <stdint.h>

// MultiHeadAttention: x(4,2048,1024) fp32; W_qkv(3072,1024); b_qkv(3072); W_o(1024,1024); b_o(1024)
// Reference does h.reshape(B,16,S,192) DIRECTLY (no transpose):
//   h[b,hh,ss,cc] = linear[b, s_orig = hh*128 + ss/16, j = (ss%16)*192 + cc]
// Pipeline: cvt(fp32->bf16) -> gemm_big<256^2, QKV scatter> -> swapped 32x32 flash attn
//           -> gemm_bt<128^2, out fp32>
// r12 = r11 resubmitted (r11 failed with an infra UnresponsiveContainer before any
// measurement; kernel audited for hangs: uniform barriers, monotone vmcnt, ordered
// ring overwrite, LDS/VGPR within budget).

typedef __attribute__((ext_vector_type(8))) short short8;
typedef __attribute__((ext_vector_type(4))) short short4v;
typedef __attribute__((ext_vector_type(4))) float f32x4;
typedef __attribute__((ext_vector_type(16))) float f32x16;

#define B_SZ 4
#define S_SZ 2048
#define H_N 16
#define DK 64
#define IN_DIM 1024
#define QKV_DIM 3072
#define MODEL 1024
#define M_ROWS (B_SZ * S_SZ)   // 8192

// Q scale: (1/sqrt(64)) * log2(e) so softmax runs in exp2 domain
#define QSCALE 0.1803368801f

#if __has_builtin(__builtin_amdgcn_exp2f)
#define EXP2(x) __builtin_amdgcn_exp2f(x)
#else
#define EXP2(x) exp2f(x)
#endif

__device__ __forceinline__ short f2bf(float f) {
    union { float f; uint32_t u; } v; v.f = f;
    uint32_t r = v.u + 0x7FFFu + ((v.u >> 16) & 1u);
    return (short)(r >> 16);
}

// pack two f32 -> two bf16 in one u32 (a in low16), RNE, single VALU op
__device__ __forceinline__ uint32_t pk2f(float a, float b) {
    uint32_t r;
    asm("v_cvt_pk_bf16_f32 %0, %1, %2" : "=v"(r) : "v"(a), "v"(b));
    return r;
}

__device__ __forceinline__ void gld_lds16(const void* g, void* l) {
    __builtin_amdgcn_global_load_lds(
        (const __attribute__((address_space(1))) void*)g,
        (__attribute__((address_space(3))) void*)l, 16, 0, 0);
}

// ---------------- fp32 -> bf16 conversion of x, W_qkv, W_o ----------------
__global__ __launch_bounds__(256) void cvt_kernel(
    const float* __restrict__ x, const float* __restrict__ wq,
    const float* __restrict__ wo, short* __restrict__ xb,
    short* __restrict__ wqb, short* __restrict__ wob) {
    const int NX = M_ROWS * IN_DIM / 4;
    const int NQ = QKV_DIM * IN_DIM / 4;
    const int NO = MODEL * IN_DIM / 4;
    const int total = NX + NQ + NO;
    for (int i = blockIdx.x * blockDim.x + threadIdx.x; i < total;
         i += gridDim.x * blockDim.x) {
        const f32x4* src; short4v* dst; int j;
        if (i < NX)           { src = (const f32x4*)x;  dst = (short4v*)xb;  j = i; }
        else if (i < NX + NQ) { src = (const f32x4*)wq; dst = (short4v*)wqb; j = i - NX; }
        else                  { src = (const f32x4*)wo; dst = (short4v*)wob; j = i - NX - NQ; }
        f32x4 v = src[j];
        short4v o;
        o[0] = f2bf(v[0]); o[1] = f2bf(v[1]); o[2] = f2bf(v[2]); o[3] = f2bf(v[3]);
        dst[j] = o;
    }
}

// ---------------- gemm_big: C = A(MxK) * B(NxK)^T + bias, QKV scatter ----------------
// 256x256 tile, BK=32, 8 waves (2M x 4N, per-wave 128x64), 4-deep LDS ring,
// counted vmcnt(8) + raw barrier. Scatter epilogue (Q scaled, K, V transposed).
__global__ __launch_bounds__(512, 1) void gemm_big(
    const short* __restrict__ A, const short* __restrict__ Bm,
    const float* __restrict__ bias,
    short* __restrict__ Qb, short* __restrict__ Kb, short* __restrict__ Vt,
    int M, int N, int K) {
    __shared__ short As[4][256 * 32];   // 64 KB
    __shared__ short Bs[4][256 * 32];   // 64 KB
    const int tid = threadIdx.x;
    const int wave = tid >> 6, lane = tid & 63;
    const int row16 = lane & 15, kgrp = lane >> 4;
    const int wrbase = (wave >> 2) * 128;   // M-rows of this wave
    const int wcbase = (wave & 3) * 64;     // N-cols of this wave
    // XCD-aware bijective swizzle (nwg = 384, % 8 == 0)
    const int nwg = gridDim.x * gridDim.y;
    const int id = blockIdx.y * gridDim.x + blockIdx.x;
    const int nid = (id & 7) * (nwg >> 3) + (id >> 3);
    const int bn = nid % gridDim.x, bm = nid / gridDim.x;
    const short* Ab = A + (size_t)bm * 256 * K;
    const short* Bb = Bm + (size_t)bn * 256 * K;
    f32x4 acc[8][4] = {};

    // Staging: 4 gld/thread/K-tile (A 2 + B 2). Thread covers rows
    // srow = wave*16 + (lane>>2) (+128); LDS chunk lane&3 (linear dest, base+lane*16);
    // global source chunk = (lane&3) ^ ((srow>>1)&3) = (lane&3) ^ ((lane>>3)&3).
    const int srow = wave * 16 + (lane >> 2);
    const int soff = ((lane & 3) ^ ((lane >> 3) & 3)) * 8;  // shorts
    const short* ag0 = Ab + (size_t)srow * K + soff;
    const short* ag1 = Ab + (size_t)(srow + 128) * K + soff;
    const short* bg0 = Bb + (size_t)srow * K + soff;
    const short* bg1 = Bb + (size_t)(srow + 128) * K + soff;
#define GSTAGE(BUF, K0)                                                        \
    {                                                                          \
        gld_lds16(ag0 + (K0), &As[BUF][(wave * 16) * 32]);                     \
        gld_lds16(ag1 + (K0), &As[BUF][(wave * 16 + 128) * 32]);               \
        gld_lds16(bg0 + (K0), &Bs[BUF][(wave * 16) * 32]);                     \
        gld_lds16(bg1 + (K0), &Bs[BUF][(wave * 16 + 128) * 32]);               \
    }
    const int NK = K >> 5;  // 32
    GSTAGE(0, 0);
    GSTAGE(1, 32);
    GSTAGE(2, 64);
    // read-side swizzle: chunk = kgrp ^ ((R>>1)&3)
    const int rch = (kgrp ^ ((row16 >> 1) & 3)) * 8;
    for (int t = 0; t < NK; ++t) {
        // my tile-t loads (issued 3 iters ago) landed; t+1, t+2 (4 each) in flight
        if (t + 2 < NK)      asm volatile("s_waitcnt vmcnt(8)" ::: "memory");
        else if (t + 1 < NK) asm volatile("s_waitcnt vmcnt(4)" ::: "memory");
        else                 asm volatile("s_waitcnt vmcnt(0)" ::: "memory");
        __builtin_amdgcn_s_barrier();   // all waves' tile-t in LDS; t-1 readers retired
        __builtin_amdgcn_sched_barrier(0);
        const int cur = t & 3;
        const int nb = (t + 3) & 3;     // buffer of tile t-1 (readers retired)
        if (t + 3 < NK) {               // stage A of t+3 now, B mid-compute
            gld_lds16(ag0 + (t + 3) * 32, &As[nb][(wave * 16) * 32]);
            gld_lds16(ag1 + (t + 3) * 32, &As[nb][(wave * 16 + 128) * 32]);
        }
        short8 bf[4];
#pragma unroll
        for (int j = 0; j < 4; ++j)
            bf[j] = *(const short8*)&Bs[cur][(wcbase + j * 16 + row16) * 32 + rch];
        __builtin_amdgcn_s_setprio(1);
#pragma unroll
        for (int i = 0; i < 4; ++i) {
            short8 af = *(const short8*)&As[cur][(wrbase + i * 16 + row16) * 32 + rch];
#pragma unroll
            for (int j = 0; j < 4; ++j)
                acc[i][j] = __builtin_amdgcn_mfma_f32_16x16x32_bf16(
                    af, bf[j], acc[i][j], 0, 0, 0);
        }
        __builtin_amdgcn_s_setprio(0);
        if (t + 3 < NK) {
            gld_lds16(bg0 + (t + 3) * 32, &Bs[nb][(wave * 16) * 32]);
            gld_lds16(bg1 + (t + 3) * 32, &Bs[nb][(wave * 16 + 128) * 32]);
        }
        __builtin_amdgcn_s_setprio(1);
#pragma unroll
        for (int i = 4; i < 8; ++i) {
            short8 af = *(const short8*)&As[cur][(wrbase + i * 16 + row16) * 32 + rch];
#pragma unroll
            for (int j = 0; j < 4; ++j)
                acc[i][j] = __builtin_amdgcn_mfma_f32_16x16x32_bf16(
                    af, bf[j], acc[i][j], 0, 0, 0);
        }
        __builtin_amdgcn_s_setprio(0);
    }
#undef GSTAGE
    // scatter epilogue (same algebra as the 128^2 kernel, verified r1-r10)
#pragma unroll
    for (int j = 0; j < 4; ++j) {
        int gcol = bn * 256 + wcbase + j * 16 + row16;
        float bv = bias[gcol];
#pragma unroll
        for (int i = 0; i < 8; ++i) {
#pragma unroll
            for (int r = 0; r < 4; ++r) {
                int grow = bm * 256 + wrbase + i * 16 + kgrp * 4 + r;
                float val = acc[i][j][r] + bv;
                int b = grow >> 11, so = grow & 2047;
                int hh = so >> 7, a = so & 127;
                int rr = gcol / 192, cc = gcol - rr * 192;
                int ss = a * 16 + rr;
                int bh = b * H_N + hh;
                if (cc < 64) {
                    Qb[(((size_t)bh) * S_SZ + ss) * DK + cc] = f2bf(val * QSCALE);
                } else if (cc < 128) {
                    Kb[(((size_t)bh) * S_SZ + ss) * DK + cc - 64] = f2bf(val);
                } else {
                    Vt[((size_t)bh * DK + (cc - 128)) * S_SZ + ss] = f2bf(val);
                }
            }
        }
    }
}

// ---------------- GEMM C = A(MxK) * B(NxK)^T + bias  (bf16 in) ----------------
// 128x128 tile, BK=32, 3-deep LDS ring (48 KB), counted vmcnt + raw barrier.
// MODE 1: fp32 linear epilogue (used for the output projection).
template <int MODE>
__global__ __launch_bounds__(256, 2) void gemm_bt(
    const short* __restrict__ A, const short* __restrict__ Bm,
    const float* __restrict__ bias, float* __restrict__ Cout,
    short* __restrict__ Qb, short* __restrict__ Kb, short* __restrict__ Vt,
    int M, int N, int K) {
    __shared__ short As[3][128 * 32];
    __shared__ short Bs[3][128 * 32];
    const int tid = threadIdx.x;
    const int wave = tid >> 6, lane = tid & 63;
    const int row16 = lane & 15, kgrp = lane >> 4;
    const int wm = (wave >> 1) * 64, wn = (wave & 1) * 64;
    const int nwg = gridDim.x * gridDim.y;
    const int id = blockIdx.y * gridDim.x + blockIdx.x;
    const int nid = (id & 7) * (nwg >> 3) + (id >> 3);
    const int bn = nid % gridDim.x, bm = nid / gridDim.x;
    const short* Ab = A + (size_t)bm * 128 * K;
    const short* Bb = Bm + (size_t)bn * 128 * K;
    f32x4 acc[4][4] = {};

    const int srow = wave * 16 + (lane >> 2);
    const int soff = ((lane & 3) ^ ((srow >> 1) & 3)) * 8;  // shorts
    const short* ag0 = Ab + (size_t)srow * K + soff;
    const short* ag1 = Ab + (size_t)(srow + 64) * K + soff;
    const short* bg0 = Bb + (size_t)srow * K + soff;
    const short* bg1 = Bb + (size_t)(srow + 64) * K + soff;
#define GSTAGE(BUF, K0)                                                        \
    {                                                                          \
        gld_lds16(ag0 + (K0), &As[BUF][(wave * 16) * 32]);                     \
        gld_lds16(ag1 + (K0), &As[BUF][(wave * 16 + 64) * 32]);                \
        gld_lds16(bg0 + (K0), &Bs[BUF][(wave * 16) * 32]);                     \
        gld_lds16(bg1 + (K0), &Bs[BUF][(wave * 16 + 64) * 32]);                \
    }

    const int NK = K >> 5;  // 32
    GSTAGE(0, 0);
    GSTAGE(1, 32);
    const int rch = (kgrp ^ ((row16 >> 1) & 3)) * 8;
    int cur = 0;
    for (int t = 0; t < NK; ++t) {
        if (t + 1 < NK) asm volatile("s_waitcnt vmcnt(4)" ::: "memory");
        else            asm volatile("s_waitcnt vmcnt(0)" ::: "memory");
        __builtin_amdgcn_s_barrier();
        __builtin_amdgcn_sched_barrier(0);
        if (t + 2 < NK) {
            int nb = cur + 2; if (nb >= 3) nb -= 3;
            GSTAGE(nb, (t + 2) * 32);
        }
        short8 af[4], bfr[4];
#pragma unroll
        for (int i = 0; i < 4; ++i)
            af[i] = *(const short8*)&As[cur][(wm + i * 16 + row16) * 32 + rch];
#pragma unroll
        for (int j = 0; j < 4; ++j)
            bfr[j] = *(const short8*)&Bs[cur][(wn + j * 16 + row16) * 32 + rch];
        __builtin_amdgcn_s_setprio(1);
#pragma unroll
        for (int i = 0; i < 4; ++i)
#pragma unroll
            for (int j = 0; j < 4; ++j)
                acc[i][j] = __builtin_amdgcn_mfma_f32_16x16x32_bf16(
                    af[i], bfr[j], acc[i][j], 0, 0, 0);
        __builtin_amdgcn_s_setprio(0);
        ++cur; if (cur == 3) cur = 0;
    }
#undef GSTAGE
#pragma unroll
    for (int j = 0; j < 4; ++j) {
        int gcol = bn * 128 + wn + j * 16 + row16;
        float bv = bias[gcol];
#pragma unroll
        for (int i = 0; i < 4; ++i) {
#pragma unroll
            for (int r = 0; r < 4; ++r) {
                int grow = bm * 128 + wm + i * 16 + kgrp * 4 + r;
                float val = acc[i][j][r] + bv;
                if (MODE == 1) {
                    Cout[(size_t)grow * N + gcol] = val;
                } else {
                    int b = grow >> 11, so = grow & 2047;
                    int hh = so >> 7, a = so & 127;
                    int rr = gcol / 192, cc = gcol - rr * 192;
                    int ss = a * 16 + rr;
                    int bh = b * H_N + hh;
                    if (cc < 64) {
                        Qb[(((size_t)bh) * S_SZ + ss) * DK + cc] = f2bf(val * QSCALE);
                    } else if (cc < 128) {
                        Kb[(((size_t)bh) * S_SZ + ss) * DK + cc - 64] = f2bf(val);
                    } else {
                        Vt[((size_t)bh * DK + (cc - 128)) * S_SZ + ss] = f2bf(val);
                    }
                }
            }
        }
    }
}

// ---------------- Swapped 32x32 flash attention ----------------
// 4 waves/block, wave owns 32 q rows; KVBLK=64 double-buffered LDS staged with
// global_load_lds (linear LDS dest, inverse-swizzled global source).
// ST[kv][q] = mfma(K, Q); softmax in-register in exp2 domain (defer-max THR=8);
// OT[d][q] = mfma(Vt, P); P B-frags built with cvt_pk + permlane32_swap.
__global__ __launch_bounds__(256, 3) void attn_kernel(
    const short* __restrict__ Qg, const short* __restrict__ Kg,
    const short* __restrict__ Vtg, short* __restrict__ O) {
    __shared__ short Ks[2][64 * 64];
    __shared__ short Vs[2][64 * 64];
    const int tid = threadIdx.x;
    const int wave = tid >> 6, lane = tid & 63;
    const int q = lane & 31, hi = lane >> 5;
    const int id = blockIdx.x;                 // 0..1023
    const int bh = (id & 7) * 8 + ((id >> 3) & 7);
    const int qt = id >> 6;                    // 0..15
    const int b = bh >> 4, h = bh & 15;
    const short* Qp = Qg + (size_t)bh * S_SZ * DK;
    const short* Kp = Kg + (size_t)bh * S_SZ * DK;
    const short* Vp = Vtg + (size_t)bh * DK * S_SZ;
    const int q0 = qt * 128 + wave * 32;

    short8 qf[4];
#pragma unroll
    for (int c = 0; c < 4; ++c)
        qf[c] = *(const short8*)&Qp[(size_t)(q0 + q) * DK + c * 16 + hi * 8];

    f32x16 ot0 = {}, ot1 = {};
    float m_run = -1e30f, l_run = 0.f;

    const int srow0 = wave * 16 + (lane >> 3);
    const int srow1 = srow0 + 8;
    const int sc0 = ((lane & 7) ^ (srow0 & 7)) * 8;   // shorts
    const int sc1 = ((lane & 7) ^ (srow1 & 7)) * 8;
    const short* kg0 = Kp + (size_t)srow0 * DK + sc0;
    const short* kg1 = Kp + (size_t)srow1 * DK + sc1;
    const short* vg0 = Vp + (size_t)srow0 * S_SZ + sc0;
    const short* vg1 = Vp + (size_t)srow1 * S_SZ + sc1;
#define STAGE(BUF)                                                              \
    {                                                                           \
        gld_lds16(kg0, &Ks[BUF][(wave * 16) * 64]);                             \
        gld_lds16(kg1, &Ks[BUF][(wave * 16 + 8) * 64]);                         \
        gld_lds16(vg0, &Vs[BUF][(wave * 16) * 64]);                             \
        gld_lds16(vg1, &Vs[BUF][(wave * 16 + 8) * 64]);                         \
        kg0 += 64 * DK; kg1 += 64 * DK; vg0 += 64; vg1 += 64;                   \
    }

    STAGE(0);

    const int NT = S_SZ / 64;  // 32
    for (int t = 0; t < NT; ++t) {
        __syncthreads();
        const int cur = t & 1;
        if (t + 1 < NT) STAGE(cur ^ 1);

        const int qx = (q & 7) << 3;
        f32x16 st0 = {}, st1 = {};
        __builtin_amdgcn_s_setprio(1);
#pragma unroll
        for (int c = 0; c < 4; ++c) {
            const int sw = (((c * 2 + hi) << 3) ^ qx);
            short8 kf0 = *(const short8*)&Ks[cur][q * 64 + sw];
            short8 kf1 = *(const short8*)&Ks[cur][(32 + q) * 64 + sw];
            st0 = __builtin_amdgcn_mfma_f32_32x32x16_bf16(kf0, qf[c], st0, 0, 0, 0);
            st1 = __builtin_amdgcn_mfma_f32_32x32x16_bf16(kf1, qf[c], st1, 0, 0, 0);
        }
        __builtin_amdgcn_s_setprio(0);

        float ma = fmaxf(fmaxf(st0[0], st0[1]), st0[2]);
        float mb = fmaxf(fmaxf(st0[8], st0[9]), st0[10]);
        float mc = fmaxf(fmaxf(st1[0], st1[1]), st1[2]);
        float md = fmaxf(fmaxf(st1[8], st1[9]), st1[10]);
        ma = fmaxf(fmaxf(ma, st0[3]), st0[4]);
        mb = fmaxf(fmaxf(mb, st0[11]), st0[12]);
        mc = fmaxf(fmaxf(mc, st1[3]), st1[4]);
        md = fmaxf(fmaxf(md, st1[11]), st1[12]);
        ma = fmaxf(fmaxf(ma, st0[5]), st0[6]);
        mb = fmaxf(fmaxf(mb, st0[13]), st0[14]);
        mc = fmaxf(fmaxf(mc, st1[5]), st1[6]);
        md = fmaxf(fmaxf(md, st1[13]), st1[14]);
        ma = fmaxf(ma, st0[7]);
        mb = fmaxf(mb, st0[15]);
        mc = fmaxf(mc, st1[7]);
        md = fmaxf(md, st1[15]);
        float pm = fmaxf(fmaxf(ma, mb), fmaxf(mc, md));
        pm = fmaxf(pm, __shfl_xor(pm, 32));
        if (__any(pm > m_run + 8.f)) {
            float mnew = fmaxf(m_run, pm);
            float corr = EXP2(m_run - mnew);
            m_run = mnew;
            l_run *= corr;
#pragma unroll
            for (int r = 0; r < 16; ++r) { ot0[r] *= corr; ot1[r] *= corr; }
        }
        float s0 = 0.f, s1 = 0.f, s2 = 0.f, s3 = 0.f;
#pragma unroll
        for (int r = 0; r < 16; r += 4) {
            st0[r] = EXP2(st0[r] - m_run);         s0 += st0[r];
            st0[r + 1] = EXP2(st0[r + 1] - m_run); s1 += st0[r + 1];
            st0[r + 2] = EXP2(st0[r + 2] - m_run); s2 += st0[r + 2];
            st0[r + 3] = EXP2(st0[r + 3] - m_run); s3 += st0[r + 3];
        }
#pragma unroll
        for (int r = 0; r < 16; r += 4) {
            st1[r] = EXP2(st1[r] - m_run);         s0 += st1[r];
            st1[r + 1] = EXP2(st1[r + 1] - m_run); s1 += st1[r + 1];
            st1[r + 2] = EXP2(st1[r + 2] - m_run); s2 += st1[r + 2];
            st1[r + 3] = EXP2(st1[r + 3] - m_run); s3 += st1[r + 3];
        }
        float ssum = (s0 + s1) + (s2 + s3);
        ssum += __shfl_xor(ssum, 32);
        l_run += ssum;

        __builtin_amdgcn_s_setprio(1);
#if __has_builtin(__builtin_amdgcn_permlane32_swap)
#define PVCHUNK(ST, B0, CH)                                                    \
    {                                                                          \
        uint32_t A01 = pk2f(ST[(B0) + 0], ST[(B0) + 1]);                       \
        uint32_t A23 = pk2f(ST[(B0) + 2], ST[(B0) + 3]);                       \
        uint32_t B45 = pk2f(ST[(B0) + 4], ST[(B0) + 5]);                       \
        uint32_t B67 = pk2f(ST[(B0) + 6], ST[(B0) + 7]);                       \
        auto sw0 = __builtin_amdgcn_permlane32_swap(A01, B45, false, false);   \
        auto sw1 = __builtin_amdgcn_permlane32_swap(A23, B67, false, false);   \
        union { uint32_t u[4]; short8 s8; } pbu;                               \
        pbu.u[0] = sw0[0]; pbu.u[1] = sw1[0];                                  \
        pbu.u[2] = sw0[1]; pbu.u[3] = sw1[1];                                  \
        const int vsw = ((((CH) * 2 + hi) << 3) ^ qx);                         \
        short8 vf0 = *(const short8*)&Vs[cur][q * 64 + vsw];                   \
        short8 vf1 = *(const short8*)&Vs[cur][(32 + q) * 64 + vsw];            \
        ot0 = __builtin_amdgcn_mfma_f32_32x32x16_bf16(vf0, pbu.s8, ot0, 0, 0, 0); \
        ot1 = __builtin_amdgcn_mfma_f32_32x32x16_bf16(vf1, pbu.s8, ot1, 0, 0, 0); \
    }
#else
#define PVCHUNK(ST, B0, CH)                                                    \
    {                                                                          \
        uint32_t A01 = pk2f(ST[(B0) + 0], ST[(B0) + 1]);                       \
        uint32_t A23 = pk2f(ST[(B0) + 2], ST[(B0) + 3]);                       \
        uint32_t B45 = pk2f(ST[(B0) + 4], ST[(B0) + 5]);                       \
        uint32_t B67 = pk2f(ST[(B0) + 6], ST[(B0) + 7]);                       \
        uint32_t t0 = hi ? A01 : B45, t1 = hi ? A23 : B67;                     \
        uint32_t r0 = (uint32_t)__shfl_xor((int)t0, 32);                       \
        uint32_t r1 = (uint32_t)__shfl_xor((int)t1, 32);                       \
        union { uint32_t u[4]; short8 s8; } pbu;                               \
        pbu.u[0] = hi ? r0 : A01; pbu.u[1] = hi ? r1 : A23;                    \
        pbu.u[2] = hi ? B45 : r0; pbu.u[3] = hi ? B67 : r1;                    \
        const int vsw = ((((CH) * 2 + hi) << 3) ^ qx);                         \
        short8 vf0 = *(const short8*)&Vs[cur][q * 64 + vsw];                   \
        short8 vf1 = *(const short8*)&Vs[cur][(32 + q) * 64 + vsw];            \
        ot0 = __builtin_amdgcn_mfma_f32_32x32x16_bf16(vf0, pbu.s8, ot0, 0, 0, 0); \
        ot1 = __builtin_amdgcn_mfma_f32_32x32x16_bf16(vf1, pbu.s8, ot1, 0, 0, 0); \
    }
#endif
        PVCHUNK(st0, 0, 0);
        PVCHUNK(st0, 8, 1);
        PVCHUNK(st1, 0, 2);
        PVCHUNK(st1, 8, 3);
#undef PVCHUNK
        __builtin_amdgcn_s_setprio(0);
    }
#undef STAGE

    float inv = 1.f / l_run;
    size_t rowbase = ((size_t)b * S_SZ + (q0 + q)) * MODEL + h * DK;
#pragma unroll
    for (int i = 0; i < 4; ++i) {
        short4v v0, v1;
#pragma unroll
        for (int jj = 0; jj < 4; ++jj) {
            v0[jj] = f2bf(ot0[4 * i + jj] * inv);
            v1[jj] = f2bf(ot1[4 * i + jj] * inv);
        }
        *(short4v*)&O[rowbase + 8 * i + 4 * hi] = v0;
        *(short4v*)&O[rowbase + 32 + 8 * i + 4 * hi] = v1;
    }
}

extern "C" void kernel_launch(void* const* d_in, const int* in_sizes, int n_in,
                              void* d_out, int out_size, void* d_ws, size_t ws_size,
                              hipStream_t stream) {
    const float* x    = (const float*)d_in[0];
    const float* Wqkv = (const float*)d_in[1];
    const float* bqkv = (const float*)d_in[2];
    const float* Wo   = (const float*)d_in[3];
    const float* bo   = (const float*)d_in[4];
    float* out = (float*)d_out;
    char* ws = (char*)d_ws;

    short* xb  = (short*)(ws + 0);           // 16 MiB
    short* wqb = (short*)(ws + 16777216);    //  6 MiB
    short* wob = (short*)(ws + 23068672);    //  2 MiB
    short* Qb  = (short*)(ws + 25165824);    // 16 MiB
    short* Kb  = (short*)(ws + 41943040);    // 16 MiB
    short* Vt  = (short*)(ws + 58720256);    // 16 MiB (transposed [bh][d][s])
    short* Ob  = (short*)(ws + 0);           // aliases xb (dead after gemm1)

    cvt_kernel<<<dim3(2048), dim3(256), 0, stream>>>(x, Wqkv, Wo, xb, wqb, wob);
    gemm_big<<<dim3(QKV_DIM / 256, M_ROWS / 256), dim3(512), 0, stream>>>(
        xb, wqb, bqkv, Qb, Kb, Vt, M_ROWS, QKV_DIM, IN_DIM);
    attn_kernel<<<dim3(1024), dim3(256), 0, stream>>>(Qb, Kb, Vt, Ob);
    gemm_bt<1><<<dim3(MODEL / 128, M_ROWS / 128), dim3(256), 0, stream>>>(
        Ob, wob, bo, out, nullptr, nullptr, nullptr, M_ROWS, MODEL, IN_DIM);
}

// Round 14
// 246.173 us; speedup vs baseline: 1.0084x; 1.0084x over previous
//
#include <hip/hip_runtime.h>
#include <stdint.h>

// MultiHeadAttention: x(4,2048,1024) fp32; W_qkv(3072,1024); b_qkv(3072); W_o(1024,1024); b_o(1024)
// Reference does h.reshape(B,16,S,192) DIRECTLY (no transpose):
//   h[b,hh,ss,cc] = linear[b, s_orig = hh*128 + ss/16, j = (ss%16)*192 + cc]
// Pipeline: cvt(fp32->bf16) -> gemm_big<256^2, QKV scatter> -> swapped 32x32 flash attn
//           -> gemm_bt<128^2, out fp32>
// r14 = r13 resubmitted (r13 failed with infra UnresponsiveContainer before any
// measurement; r12 proved the container failures are not kernel-induced by running
// the identical r11 source successfully). gemm_big: VERBATIM T3 minimum-2-phase at
// 256^2/BK=64/8 waves (m248v2: 655-666 TF refcheck'd at K=1024 for this structure).

typedef __attribute__((ext_vector_type(8))) short short8;
typedef __attribute__((ext_vector_type(4))) short short4v;
typedef __attribute__((ext_vector_type(4))) float f32x4;
typedef __attribute__((ext_vector_type(16))) float f32x16;

#define B_SZ 4
#define S_SZ 2048
#define H_N 16
#define DK 64
#define IN_DIM 1024
#define QKV_DIM 3072
#define MODEL 1024
#define M_ROWS (B_SZ * S_SZ)   // 8192

// Q scale: (1/sqrt(64)) * log2(e) so softmax runs in exp2 domain
#define QSCALE 0.1803368801f

#if __has_builtin(__builtin_amdgcn_exp2f)
#define EXP2(x) __builtin_amdgcn_exp2f(x)
#else
#define EXP2(x) exp2f(x)
#endif

__device__ __forceinline__ short f2bf(float f) {
    union { float f; uint32_t u; } v; v.f = f;
    uint32_t r = v.u + 0x7FFFu + ((v.u >> 16) & 1u);
    return (short)(r >> 16);
}

// pack two f32 -> two bf16 in one u32 (a in low16), RNE, single VALU op
__device__ __forceinline__ uint32_t pk2f(float a, float b) {
    uint32_t r;
    asm("v_cvt_pk_bf16_f32 %0, %1, %2" : "=v"(r) : "v"(a), "v"(b));
    return r;
}

__device__ __forceinline__ void gld_lds16(const void* g, void* l) {
    __builtin_amdgcn_global_load_lds(
        (const __attribute__((address_space(1))) void*)g,
        (__attribute__((address_space(3))) void*)l, 16, 0, 0);
}

// ---------------- fp32 -> bf16 conversion of x, W_qkv, W_o ----------------
__global__ __launch_bounds__(256) void cvt_kernel(
    const float* __restrict__ x, const float* __restrict__ wq,
    const float* __restrict__ wo, short* __restrict__ xb,
    short* __restrict__ wqb, short* __restrict__ wob) {
    const int NX = M_ROWS * IN_DIM / 4;
    const int NQ = QKV_DIM * IN_DIM / 4;
    const int NO = MODEL * IN_DIM / 4;
    const int total = NX + NQ + NO;
    for (int i = blockIdx.x * blockDim.x + threadIdx.x; i < total;
         i += gridDim.x * blockDim.x) {
        const f32x4* src; short4v* dst; int j;
        if (i < NX)           { src = (const f32x4*)x;  dst = (short4v*)xb;  j = i; }
        else if (i < NX + NQ) { src = (const f32x4*)wq; dst = (short4v*)wqb; j = i - NX; }
        else                  { src = (const f32x4*)wo; dst = (short4v*)wob; j = i - NX - NQ; }
        f32x4 v = src[j];
        short4v o;
        o[0] = f2bf(v[0]); o[1] = f2bf(v[1]); o[2] = f2bf(v[2]); o[3] = f2bf(v[3]);
        dst[j] = o;
    }
}

// ---------------- gemm_big: C = A(MxK) * B(NxK)^T + bias, QKV scatter ----------------
// 256x256 tile, BK=64, 8 waves (2M x 4N, per-wave 128x64), double-buffered LDS
// (128 KB), T3 minimum-2-phase schedule: STAGE(next) -> ds_read -> 64 MFMA ->
// one __syncthreads() per K-tile.
__global__ __launch_bounds__(512, 1) void gemm_big(
    const short* __restrict__ A, const short* __restrict__ Bm,
    const float* __restrict__ bias,
    short* __restrict__ Qb, short* __restrict__ Kb, short* __restrict__ Vt,
    int M, int N, int K) {
    __shared__ short As[2][256 * 64];   // 64 KB
    __shared__ short Bs[2][256 * 64];   // 64 KB
    const int tid = threadIdx.x;
    const int wave = tid >> 6, lane = tid & 63;
    const int row16 = lane & 15, kgrp = lane >> 4;
    const int wrbase = (wave >> 2) * 128;   // M-rows of this wave
    const int wcbase = (wave & 3) * 64;     // N-cols of this wave
    // XCD-aware bijective swizzle (nwg = 384, % 8 == 0)
    const int nwg = gridDim.x * gridDim.y;
    const int id = blockIdx.y * gridDim.x + blockIdx.x;
    const int nid = (id & 7) * (nwg >> 3) + (id >> 3);
    const int bn = nid % gridDim.x, bm = nid / gridDim.x;
    const short* Ab = A + (size_t)bm * 256 * K;
    const short* Bb = Bm + (size_t)bn * 256 * K;
    f32x4 acc[8][4] = {};

    // Staging: 8 gld/thread/K-tile (A 4 + B 4). Load-step l covers rows
    // [wave*8 + l*64, +8); lane: row = base + (lane>>3), LDS chunk lane&7
    // (linear dest = base + lane*16B); global source chunk = (lane&7)^(row&7)
    // = (lane&7)^(lane>>3). Read side XORs chunk with (R&7) — same involution
    // measured 0-conflict in r12.
    const int soff = ((lane & 7) ^ (lane >> 3)) * 8;  // shorts
    const int srow = wave * 8 + (lane >> 3);
#define GSTAGE(BUF, K0)                                                        \
    {                                                                          \
        _Pragma("unroll") for (int l = 0; l < 4; ++l) {                        \
            gld_lds16(Ab + (size_t)(srow + l * 64) * K + (K0) + soff,          \
                      &As[BUF][(wave * 8 + l * 64) * 64]);                     \
            gld_lds16(Bb + (size_t)(srow + l * 64) * K + (K0) + soff,         \
                      &Bs[BUF][(wave * 8 + l * 64) * 64]);                     \
        }                                                                      \
    }
    const int NK = K >> 6;  // 16
    GSTAGE(0, 0);
    __syncthreads();
    int cur = 0;
    for (int t = 0; t < NK; ++t) {
        if (t + 1 < NK) GSTAGE(cur ^ 1, (t + 1) * 64);  // in flight across compute
        // B-frags: row R = wcbase + j*16 + row16, chunk (kk*4+kgrp)^(R&7)
        short8 bf[4][2];
#pragma unroll
        for (int j = 0; j < 4; ++j) {
            int R = wcbase + j * 16 + row16;
#pragma unroll
            for (int kk = 0; kk < 2; ++kk)
                bf[j][kk] = *(const short8*)
                    &Bs[cur][R * 64 + (((kk * 4 + kgrp) ^ (R & 7)) * 8)];
        }
        __builtin_amdgcn_s_setprio(1);
#pragma unroll
        for (int kk = 0; kk < 2; ++kk)
#pragma unroll
            for (int i = 0; i < 8; ++i) {
                int R = wrbase + i * 16 + row16;
                short8 af = *(const short8*)
                    &As[cur][R * 64 + (((kk * 4 + kgrp) ^ (R & 7)) * 8)];
#pragma unroll
                for (int j = 0; j < 4; ++j)
                    acc[i][j] = __builtin_amdgcn_mfma_f32_16x16x32_bf16(
                        af, bf[j][kk], acc[i][j], 0, 0, 0);
            }
        __builtin_amdgcn_s_setprio(0);
        __syncthreads();   // drains vmcnt -> tile t+1 staged; buf^1 readers retired
        cur ^= 1;
    }
#undef GSTAGE
    // scatter epilogue (same algebra as the 128^2 kernel, verified r1-r12)
#pragma unroll
    for (int j = 0; j < 4; ++j) {
        int gcol = bn * 256 + wcbase + j * 16 + row16;
        float bv = bias[gcol];
#pragma unroll
        for (int i = 0; i < 8; ++i) {
#pragma unroll
            for (int r = 0; r < 4; ++r) {
                int grow = bm * 256 + wrbase + i * 16 + kgrp * 4 + r;
                float val = acc[i][j][r] + bv;
                int b = grow >> 11, so = grow & 2047;
                int hh = so >> 7, a = so & 127;
                int rr = gcol / 192, cc = gcol - rr * 192;
                int ss = a * 16 + rr;
                int bh = b * H_N + hh;
                if (cc < 64) {
                    Qb[(((size_t)bh) * S_SZ + ss) * DK + cc] = f2bf(val * QSCALE);
                } else if (cc < 128) {
                    Kb[(((size_t)bh) * S_SZ + ss) * DK + cc - 64] = f2bf(val);
                } else {
                    Vt[((size_t)bh * DK + (cc - 128)) * S_SZ + ss] = f2bf(val);
                }
            }
        }
    }
}

// ---------------- GEMM C = A(MxK) * B(NxK)^T + bias  (bf16 in) ----------------
// 128x128 tile, BK=32, 3-deep LDS ring (48 KB), counted vmcnt + raw barrier.
// MODE 1: fp32 linear epilogue (used for the output projection).
template <int MODE>
__global__ __launch_bounds__(256, 2) void gemm_bt(
    const short* __restrict__ A, const short* __restrict__ Bm,
    const float* __restrict__ bias, float* __restrict__ Cout,
    short* __restrict__ Qb, short* __restrict__ Kb, short* __restrict__ Vt,
    int M, int N, int K) {
    __shared__ short As[3][128 * 32];
    __shared__ short Bs[3][128 * 32];
    const int tid = threadIdx.x;
    const int wave = tid >> 6, lane = tid & 63;
    const int row16 = lane & 15, kgrp = lane >> 4;
    const int wm = (wave >> 1) * 64, wn = (wave & 1) * 64;
    const int nwg = gridDim.x * gridDim.y;
    const int id = blockIdx.y * gridDim.x + blockIdx.x;
    const int nid = (id & 7) * (nwg >> 3) + (id >> 3);
    const int bn = nid % gridDim.x, bm = nid / gridDim.x;
    const short* Ab = A + (size_t)bm * 128 * K;
    const short* Bb = Bm + (size_t)bn * 128 * K;
    f32x4 acc[4][4] = {};

    const int srow = wave * 16 + (lane >> 2);
    const int soff = ((lane & 3) ^ ((srow >> 1) & 3)) * 8;  // shorts
    const short* ag0 = Ab + (size_t)srow * K + soff;
    const short* ag1 = Ab + (size_t)(srow + 64) * K + soff;
    const short* bg0 = Bb + (size_t)srow * K + soff;
    const short* bg1 = Bb + (size_t)(srow + 64) * K + soff;
#define GSTAGE(BUF, K0)                                                        \
    {                                                                          \
        gld_lds16(ag0 + (K0), &As[BUF][(wave * 16) * 32]);                     \
        gld_lds16(ag1 + (K0), &As[BUF][(wave * 16 + 64) * 32]);                \
        gld_lds16(bg0 + (K0), &Bs[BUF][(wave * 16) * 32]);                     \
        gld_lds16(bg1 + (K0), &Bs[BUF][(wave * 16 + 64) * 32]);                \
    }

    const int NK = K >> 5;  // 32
    GSTAGE(0, 0);
    GSTAGE(1, 32);
    const int rch = (kgrp ^ ((row16 >> 1) & 3)) * 8;
    int cur = 0;
    for (int t = 0; t < NK; ++t) {
        if (t + 1 < NK) asm volatile("s_waitcnt vmcnt(4)" ::: "memory");
        else            asm volatile("s_waitcnt vmcnt(0)" ::: "memory");
        __builtin_amdgcn_s_barrier();
        __builtin_amdgcn_sched_barrier(0);
        if (t + 2 < NK) {
            int nb = cur + 2; if (nb >= 3) nb -= 3;
            GSTAGE(nb, (t + 2) * 32);
        }
        short8 af[4], bfr[4];
#pragma unroll
        for (int i = 0; i < 4; ++i)
            af[i] = *(const short8*)&As[cur][(wm + i * 16 + row16) * 32 + rch];
#pragma unroll
        for (int j = 0; j < 4; ++j)
            bfr[j] = *(const short8*)&Bs[cur][(wn + j * 16 + row16) * 32 + rch];
        __builtin_amdgcn_s_setprio(1);
#pragma unroll
        for (int i = 0; i < 4; ++i)
#pragma unroll
            for (int j = 0; j < 4; ++j)
                acc[i][j] = __builtin_amdgcn_mfma_f32_16x16x32_bf16(
                    af[i], bfr[j], acc[i][j], 0, 0, 0);
        __builtin_amdgcn_s_setprio(0);
        ++cur; if (cur == 3) cur = 0;
    }
#undef GSTAGE
#pragma unroll
    for (int j = 0; j < 4; ++j) {
        int gcol = bn * 128 + wn + j * 16 + row16;
        float bv = bias[gcol];
#pragma unroll
        for (int i = 0; i < 4; ++i) {
#pragma unroll
            for (int r = 0; r < 4; ++r) {
                int grow = bm * 128 + wm + i * 16 + kgrp * 4 + r;
                float val = acc[i][j][r] + bv;
                if (MODE == 1) {
                    Cout[(size_t)grow * N + gcol] = val;
                } else {
                    int b = grow >> 11, so = grow & 2047;
                    int hh = so >> 7, a = so & 127;
                    int rr = gcol / 192, cc = gcol - rr * 192;
                    int ss = a * 16 + rr;
                    int bh = b * H_N + hh;
                    if (cc < 64) {
                        Qb[(((size_t)bh) * S_SZ + ss) * DK + cc] = f2bf(val * QSCALE);
                    } else if (cc < 128) {
                        Kb[(((size_t)bh) * S_SZ + ss) * DK + cc - 64] = f2bf(val);
                    } else {
                        Vt[((size_t)bh * DK + (cc - 128)) * S_SZ + ss] = f2bf(val);
                    }
                }
            }
        }
    }
}

// ---------------- Swapped 32x32 flash attention ----------------
// 4 waves/block, wave owns 32 q rows; KVBLK=64 double-buffered LDS staged with
// global_load_lds (linear LDS dest, inverse-swizzled global source).
// ST[kv][q] = mfma(K, Q); softmax in-register in exp2 domain (defer-max THR=8);
// OT[d][q] = mfma(Vt, P); P B-frags built with cvt_pk + permlane32_swap.
__global__ __launch_bounds__(256, 3) void attn_kernel(
    const short* __restrict__ Qg, const short* __restrict__ Kg,
    const short* __restrict__ Vtg, short* __restrict__ O) {
    __shared__ short Ks[2][64 * 64];
    __shared__ short Vs[2][64 * 64];
    const int tid = threadIdx.x;
    const int wave = tid >> 6, lane = tid & 63;
    const int q = lane & 31, hi = lane >> 5;
    const int id = blockIdx.x;                 // 0..1023
    const int bh = (id & 7) * 8 + ((id >> 3) & 7);
    const int qt = id >> 6;                    // 0..15
    const int b = bh >> 4, h = bh & 15;
    const short* Qp = Qg + (size_t)bh * S_SZ * DK;
    const short* Kp = Kg + (size_t)bh * S_SZ * DK;
    const short* Vp = Vtg + (size_t)bh * DK * S_SZ;
    const int q0 = qt * 128 + wave * 32;

    short8 qf[4];
#pragma unroll
    for (int c = 0; c < 4; ++c)
        qf[c] = *(const short8*)&Qp[(size_t)(q0 + q) * DK + c * 16 + hi * 8];

    f32x16 ot0 = {}, ot1 = {};
    float m_run = -1e30f, l_run = 0.f;

    const int srow0 = wave * 16 + (lane >> 3);
    const int srow1 = srow0 + 8;
    const int sc0 = ((lane & 7) ^ (srow0 & 7)) * 8;   // shorts
    const int sc1 = ((lane & 7) ^ (srow1 & 7)) * 8;
    const short* kg0 = Kp + (size_t)srow0 * DK + sc0;
    const short* kg1 = Kp + (size_t)srow1 * DK + sc1;
    const short* vg0 = Vp + (size_t)srow0 * S_SZ + sc0;
    const short* vg1 = Vp + (size_t)srow1 * S_SZ + sc1;
#define STAGE(BUF)                                                              \
    {                                                                           \
        gld_lds16(kg0, &Ks[BUF][(wave * 16) * 64]);                             \
        gld_lds16(kg1, &Ks[BUF][(wave * 16 + 8) * 64]);                         \
        gld_lds16(vg0, &Vs[BUF][(wave * 16) * 64]);                             \
        gld_lds16(vg1, &Vs[BUF][(wave * 16 + 8) * 64]);                         \
        kg0 += 64 * DK; kg1 += 64 * DK; vg0 += 64; vg1 += 64;                   \
    }

    STAGE(0);

    const int NT = S_SZ / 64;  // 32
    for (int t = 0; t < NT; ++t) {
        __syncthreads();
        const int cur = t & 1;
        if (t + 1 < NT) STAGE(cur ^ 1);

        const int qx = (q & 7) << 3;
        f32x16 st0 = {}, st1 = {};
        __builtin_amdgcn_s_setprio(1);
#pragma unroll
        for (int c = 0; c < 4; ++c) {
            const int sw = (((c * 2 + hi) << 3) ^ qx);
            short8 kf0 = *(const short8*)&Ks[cur][q * 64 + sw];
            short8 kf1 = *(const short8*)&Ks[cur][(32 + q) * 64 + sw];
            st0 = __builtin_amdgcn_mfma_f32_32x32x16_bf16(kf0, qf[c], st0, 0, 0, 0);
            st1 = __builtin_amdgcn_mfma_f32_32x32x16_bf16(kf1, qf[c], st1, 0, 0, 0);
        }
        __builtin_amdgcn_s_setprio(0);

        float ma = fmaxf(fmaxf(st0[0], st0[1]), st0[2]);
        float mb = fmaxf(fmaxf(st0[8], st0[9]), st0[10]);
        float mc = fmaxf(fmaxf(st1[0], st1[1]), st1[2]);
        float md = fmaxf(fmaxf(st1[8], st1[9]), st1[10]);
        ma = fmaxf(fmaxf(ma, st0[3]), st0[4]);
        mb = fmaxf(fmaxf(mb, st0[11]), st0[12]);
        mc = fmaxf(fmaxf(mc, st1[3]), st1[4]);
        md = fmaxf(fmaxf(md, st1[11]), st1[12]);
        ma = fmaxf(fmaxf(ma, st0[5]), st0[6]);
        mb = fmaxf(fmaxf(mb, st0[13]), st0[14]);
        mc = fmaxf(fmaxf(mc, st1[5]), st1[6]);
        md = fmaxf(fmaxf(md, st1[13]), st1[14]);
        ma = fmaxf(ma, st0[7]);
        mb = fmaxf(mb, st0[15]);
        mc = fmaxf(mc, st1[7]);
        md = fmaxf(md, st1[15]);
        float pm = fmaxf(fmaxf(ma, mb), fmaxf(mc, md));
        pm = fmaxf(pm, __shfl_xor(pm, 32));
        if (__any(pm > m_run + 8.f)) {
            float mnew = fmaxf(m_run, pm);
            float corr = EXP2(m_run - mnew);
            m_run = mnew;
            l_run *= corr;
#pragma unroll
            for (int r = 0; r < 16; ++r) { ot0[r] *= corr; ot1[r] *= corr; }
        }
        float s0 = 0.f, s1 = 0.f, s2 = 0.f, s3 = 0.f;
#pragma unroll
        for (int r = 0; r < 16; r += 4) {
            st0[r] = EXP2(st0[r] - m_run);         s0 += st0[r];
            st0[r + 1] = EXP2(st0[r + 1] - m_run); s1 += st0[r + 1];
            st0[r + 2] = EXP2(st0[r + 2] - m_run); s2 += st0[r + 2];
            st0[r + 3] = EXP2(st0[r + 3] - m_run); s3 += st0[r + 3];
        }
#pragma unroll
        for (int r = 0; r < 16; r += 4) {
            st1[r] = EXP2(st1[r] - m_run);         s0 += st1[r];
            st1[r + 1] = EXP2(st1[r + 1] - m_run); s1 += st1[r + 1];
            st1[r + 2] = EXP2(st1[r + 2] - m_run); s2 += st1[r + 2];
            st1[r + 3] = EXP2(st1[r + 3] - m_run); s3 += st1[r + 3];
        }
        float ssum = (s0 + s1) + (s2 + s3);
        ssum += __shfl_xor(ssum, 32);
        l_run += ssum;

        __builtin_amdgcn_s_setprio(1);
#if __has_builtin(__builtin_amdgcn_permlane32_swap)
#define PVCHUNK(ST, B0, CH)                                                    \
    {                                                                          \
        uint32_t A01 = pk2f(ST[(B0) + 0], ST[(B0) + 1]);                       \
        uint32_t A23 = pk2f(ST[(B0) + 2], ST[(B0) + 3]);                       \
        uint32_t B45 = pk2f(ST[(B0) + 4], ST[(B0) + 5]);                       \
        uint32_t B67 = pk2f(ST[(B0) + 6], ST[(B0) + 7]);                       \
        auto sw0 = __builtin_amdgcn_permlane32_swap(A01, B45, false, false);   \
        auto sw1 = __builtin_amdgcn_permlane32_swap(A23, B67, false, false);   \
        union { uint32_t u[4]; short8 s8; } pbu;                               \
        pbu.u[0] = sw0[0]; pbu.u[1] = sw1[0];                                  \
        pbu.u[2] = sw0[1]; pbu.u[3] = sw1[1];                                  \
        const int vsw = ((((CH) * 2 + hi) << 3) ^ qx);                         \
        short8 vf0 = *(const short8*)&Vs[cur][q * 64 + vsw];                   \
        short8 vf1 = *(const short8*)&Vs[cur][(32 + q) * 64 + vsw];            \
        ot0 = __builtin_amdgcn_mfma_f32_32x32x16_bf16(vf0, pbu.s8, ot0, 0, 0, 0); \
        ot1 = __builtin_amdgcn_mfma_f32_32x32x16_bf16(vf1, pbu.s8, ot1, 0, 0, 0); \
    }
#else
#define PVCHUNK(ST, B0, CH)                                                    \
    {                                                                          \
        uint32_t A01 = pk2f(ST[(B0) + 0], ST[(B0) + 1]);                       \
        uint32_t A23 = pk2f(ST[(B0) + 2], ST[(B0) + 3]);                       \
        uint32_t B45 = pk2f(ST[(B0) + 4], ST[(B0) + 5]);                       \
        uint32_t B67 = pk2f(ST[(B0) + 6], ST[(B0) + 7]);                       \
        uint32_t t0 = hi ? A01 : B45, t1 = hi ? A23 : B67;                     \
        uint32_t r0 = (uint32_t)__shfl_xor((int)t0, 32);                       \
        uint32_t r1 = (uint32_t)__shfl_xor((int)t1, 32);                       \
        union { uint32_t u[4]; short8 s8; } pbu;                               \
        pbu.u[0] = hi ? r0 : A01; pbu.u[1] = hi ? r1 : A23;                    \
        pbu.u[2] = hi ? B45 : r0; pbu.u[3] = hi ? B67 : r1;                    \
        const int vsw = ((((CH) * 2 + hi) << 3) ^ qx);                         \
        short8 vf0 = *(const short8*)&Vs[cur][q * 64 + vsw];                   \
        short8 vf1 = *(const short8*)&Vs[cur][(32 + q) * 64 + vsw];            \
        ot0 = __builtin_amdgcn_mfma_f32_32x32x16_bf16(vf0, pbu.s8, ot0, 0, 0, 0); \
        ot1 = __builtin_amdgcn_mfma_f32_32x32x16_bf16(vf1, pbu.s8, ot1, 0, 0, 0); \
    }
#endif
        PVCHUNK(st0, 0, 0);
        PVCHUNK(st0, 8, 1);
        PVCHUNK(st1, 0, 2);
        PVCHUNK(st1, 8, 3);
#undef PVCHUNK
        __builtin_amdgcn_s_setprio(0);
    }
#undef STAGE

    float inv = 1.f / l_run;
    size_t rowbase = ((size_t)b * S_SZ + (q0 + q)) * MODEL + h * DK;
#pragma unroll
    for (int i = 0; i < 4; ++i) {
        short4v v0, v1;
#pragma unroll
        for (int jj = 0; jj < 4; ++jj) {
            v0[jj] = f2bf(ot0[4 * i + jj] * inv);
            v1[jj] = f2bf(ot1[4 * i + jj] * inv);
        }
        *(short4v*)&O[rowbase + 8 * i + 4 * hi] = v0;
        *(short4v*)&O[rowbase + 32 + 8 * i + 4 * hi] = v1;
    }
}

extern "C" void kernel_launch(void* const* d_in, const int* in_sizes, int n_in,
                              void* d_out, int out_size, void* d_ws, size_t ws_size,
                              hipStream_t stream) {
    const float* x    = (const float*)d_in[0];
    const float* Wqkv = (const float*)d_in[1];
    const float* bqkv = (const float*)d_in[2];
    const float* Wo   = (const float*)d_in[3];
    const float* bo   = (const float*)d_in[4];
    float* out = (float*)d_out;
    char* ws = (char*)d_ws;

    short* xb  = (short*)(ws + 0);           // 16 MiB
    short* wqb = (short*)(ws + 16777216);    //  6 MiB
    short* wob = (short*)(ws + 23068672);    //  2 MiB
    short* Qb  = (short*)(ws + 25165824);    // 16 MiB
    short* Kb  = (short*)(ws + 41943040);    // 16 MiB
    short* Vt  = (short*)(ws + 58720256);    // 16 MiB (transposed [bh][d][s])
    short* Ob  = (short*)(ws + 0);           // aliases xb (dead after gemm1)

    cvt_kernel<<<dim3(2048), dim3(256), 0, stream>>>(x, Wqkv, Wo, xb, wqb, wob);
    gemm_big<<<dim3(QKV_DIM / 256, M_ROWS / 256), dim3(512), 0, stream>>>(
        xb, wqb, bqkv, Qb, Kb, Vt, M_ROWS, QKV_DIM, IN_DIM);
    attn_kernel<<<dim3(1024), dim3(256), 0, stream>>>(Qb, Kb, Vt, Ob);
    gemm_bt<1><<<dim3(MODEL / 128, M_ROWS / 128), dim3(256), 0, stream>>>(
        Ob, wob, bo, out, nullptr, nullptr, nullptr, M_ROWS, MODEL, IN_DIM);
}

// Round 16
// 225.022 us; speedup vs baseline: 1.1032x; 1.0940x over previous
//
#include <hip/hip_runtime.h>
#include <stdint.h>

// MultiHeadAttention: x(4,2048,1024) fp32; W_qkv(3072,1024); b_qkv(3072); W_o(1024,1024); b_o(1024)
// Reference does h.reshape(B,16,S,192) DIRECTLY (no transpose):
//   h[b,hh,ss,cc] = linear[b, s_orig = hh*128 + ss/16, j = (ss%16)*192 + cc]
// Pipeline: cvt(fp32->bf16) -> gemm_bt<QKV scatter (Q pre-scaled by log2e/8, V transposed)> ->
//           swapped 32x32 flash attn -> gemm_bt<out fp32>
// r16 = r15 resubmitted (r15 lost to infra UnresponsiveContainer; this source is
// byte-identical to round-6 which measured 225.35 us, passed, absmax 4.88e-4).
// Session summary: 2-phase gemm family fully bracketed (r4-r14: 413-490 TF,
// MfmaUtil 16-19% across BK/depth/tile variants — stage+sync overhead is
// structural per m233); attn at ~915 TF-effective via swapped-QK^T in-register
// softmax ladder. This is the measured session optimum.

typedef __attribute__((ext_vector_type(8))) short short8;
typedef __attribute__((ext_vector_type(4))) short short4v;
typedef __attribute__((ext_vector_type(4))) float f32x4;
typedef __attribute__((ext_vector_type(16))) float f32x16;

#define B_SZ 4
#define S_SZ 2048
#define H_N 16
#define DK 64
#define IN_DIM 1024
#define QKV_DIM 3072
#define MODEL 1024
#define M_ROWS (B_SZ * S_SZ)   // 8192

// Q scale: (1/sqrt(64)) * log2(e) so softmax runs in exp2 domain
#define QSCALE 0.1803368801f

#if __has_builtin(__builtin_amdgcn_exp2f)
#define EXP2(x) __builtin_amdgcn_exp2f(x)
#else
#define EXP2(x) exp2f(x)
#endif

__device__ __forceinline__ short f2bf(float f) {
    union { float f; uint32_t u; } v; v.f = f;
    uint32_t r = v.u + 0x7FFFu + ((v.u >> 16) & 1u);
    return (short)(r >> 16);
}

// pack two f32 -> two bf16 in one u32 (a in low16), RNE, single VALU op
__device__ __forceinline__ uint32_t pk2f(float a, float b) {
    uint32_t r;
    asm("v_cvt_pk_bf16_f32 %0, %1, %2" : "=v"(r) : "v"(a), "v"(b));
    return r;
}

__device__ __forceinline__ void gld_lds16(const void* g, void* l) {
    __builtin_amdgcn_global_load_lds(
        (const __attribute__((address_space(1))) void*)g,
        (__attribute__((address_space(3))) void*)l, 16, 0, 0);
}

// ---------------- fp32 -> bf16 conversion of x, W_qkv, W_o ----------------
__global__ __launch_bounds__(256) void cvt_kernel(
    const float* __restrict__ x, const float* __restrict__ wq,
    const float* __restrict__ wo, short* __restrict__ xb,
    short* __restrict__ wqb, short* __restrict__ wob) {
    const int NX = M_ROWS * IN_DIM / 4;
    const int NQ = QKV_DIM * IN_DIM / 4;
    const int NO = MODEL * IN_DIM / 4;
    const int total = NX + NQ + NO;
    for (int i = blockIdx.x * blockDim.x + threadIdx.x; i < total;
         i += gridDim.x * blockDim.x) {
        const f32x4* src; short4v* dst; int j;
        if (i < NX)           { src = (const f32x4*)x;  dst = (short4v*)xb;  j = i; }
        else if (i < NX + NQ) { src = (const f32x4*)wq; dst = (short4v*)wqb; j = i - NX; }
        else                  { src = (const f32x4*)wo; dst = (short4v*)wob; j = i - NX - NQ; }
        f32x4 v = src[j];
        short4v o;
        o[0] = f2bf(v[0]); o[1] = f2bf(v[1]); o[2] = f2bf(v[2]); o[3] = f2bf(v[3]);
        dst[j] = o;
    }
}

// ---------------- GEMM C = A(MxK) * B(NxK)^T + bias  (bf16 in) ----------------
// 128x128 tile, BK=64, double-buffered LDS (XOR-swizzled), T3-minimum pipeline.
// MODE 0: scatter epilogue into Q (scaled QSCALE) / K / Vt (transposed). MODE 1: fp32 epilogue.
template <int MODE>
__global__ __launch_bounds__(256, 2) void gemm_bt(
    const short* __restrict__ A, const short* __restrict__ Bm,
    const float* __restrict__ bias, float* __restrict__ Cout,
    short* __restrict__ Qb, short* __restrict__ Kb, short* __restrict__ Vt,
    int M, int N, int K) {
    __shared__ short As[2][128 * 64];
    __shared__ short Bs[2][128 * 64];
    const int tid = threadIdx.x;
    const int wave = tid >> 6, lane = tid & 63;
    const int row16 = lane & 15, kgrp = lane >> 4;
    const int wm = (wave >> 1) * 64, wn = (wave & 1) * 64;
    // XCD-aware bijective swizzle (nwg % 8 == 0 for both launches)
    const int nwg = gridDim.x * gridDim.y;
    const int id = blockIdx.y * gridDim.x + blockIdx.x;
    const int nid = (id & 7) * (nwg >> 3) + (id >> 3);
    const int bn = nid % gridDim.x, bm = nid / gridDim.x;
    const short* Ab = A + (size_t)bm * 128 * K;
    const short* Bb = Bm + (size_t)bn * 128 * K;
    f32x4 acc[4][4] = {};

    // Staging: load l covers rows [wave*8 + l*32, +8); lane -> row base+(lane>>3),
    // LDS chunk lane&7 (linear dest); global source chunk = (lane&7)^(lane>>3).
    const int soff = ((lane & 7) ^ (lane >> 3)) * 8;  // shorts, within 64-col row
#define GSTAGE(BUF, K0)                                                        \
    {                                                                          \
        _Pragma("unroll") for (int l = 0; l < 4; ++l) {                        \
            int r = wave * 8 + (lane >> 3) + l * 32;                           \
            gld_lds16(Ab + (size_t)r * K + (K0) + soff,                        \
                      &As[BUF][(wave * 8 + l * 32) * 64]);                     \
            gld_lds16(Bb + (size_t)r * K + (K0) + soff,                        \
                      &Bs[BUF][(wave * 8 + l * 32) * 64]);                     \
        }                                                                      \
    }

    GSTAGE(0, 0);
    const int NK = K >> 6;  // 16
    for (int t = 0; t < NK; ++t) {
        __syncthreads();   // drains vmcnt -> tile t staged (issued one compute ago)
        const int cur = t & 1;
        if (t + 1 < NK) GSTAGE(cur ^ 1, (t + 1) * 64);  // in flight across compute
#pragma unroll
        for (int kk = 0; kk < 2; ++kk) {
            short8 af[4], bfr[4];
#pragma unroll
            for (int i = 0; i < 4; ++i) {
                int R = wm + i * 16 + row16;
                int ch = (kk * 4 + kgrp) ^ (R & 7);
                af[i] = *(const short8*)&As[cur][R * 64 + ch * 8];
            }
#pragma unroll
            for (int j = 0; j < 4; ++j) {
                int R = wn + j * 16 + row16;
                int ch = (kk * 4 + kgrp) ^ (R & 7);
                bfr[j] = *(const short8*)&Bs[cur][R * 64 + ch * 8];
            }
            __builtin_amdgcn_s_setprio(1);
#pragma unroll
            for (int i = 0; i < 4; ++i)
#pragma unroll
                for (int j = 0; j < 4; ++j)
                    acc[i][j] = __builtin_amdgcn_mfma_f32_16x16x32_bf16(
                        af[i], bfr[j], acc[i][j], 0, 0, 0);
            __builtin_amdgcn_s_setprio(0);
        }
    }
#undef GSTAGE
#pragma unroll
    for (int j = 0; j < 4; ++j) {
        int gcol = bn * 128 + wn + j * 16 + row16;
        float bv = bias[gcol];
#pragma unroll
        for (int i = 0; i < 4; ++i) {
#pragma unroll
            for (int r = 0; r < 4; ++r) {
                int grow = bm * 128 + wm + i * 16 + kgrp * 4 + r;
                float val = acc[i][j][r] + bv;
                if (MODE == 1) {
                    Cout[(size_t)grow * N + gcol] = val;
                } else {
                    int b = grow >> 11, so = grow & 2047;
                    int hh = so >> 7, a = so & 127;
                    int rr = gcol / 192, cc = gcol - rr * 192;
                    int ss = a * 16 + rr;
                    int bh = b * H_N + hh;
                    if (cc < 64) {
                        Qb[(((size_t)bh) * S_SZ + ss) * DK + cc] = f2bf(val * QSCALE);
                    } else if (cc < 128) {
                        Kb[(((size_t)bh) * S_SZ + ss) * DK + cc - 64] = f2bf(val);
                    } else {
                        // V stored TRANSPOSED: Vt[bh][d][s]
                        Vt[((size_t)bh * DK + (cc - 128)) * S_SZ + ss] = f2bf(val);
                    }
                }
            }
        }
    }
}

// ---------------- Swapped 32x32 flash attention ----------------
// 4 waves/block, wave owns 32 q rows; KVBLK=64 double-buffered LDS staged with
// global_load_lds (linear LDS dest, inverse-swizzled global source).
// ST[kv][q] = mfma(K, Q); softmax in-register in exp2 domain (defer-max THR=8);
// OT[d][q] = mfma(Vt, P); P B-frags built with cvt_pk + permlane32_swap.
__global__ __launch_bounds__(256, 3) void attn_kernel(
    const short* __restrict__ Qg, const short* __restrict__ Kg,
    const short* __restrict__ Vtg, short* __restrict__ O) {
    __shared__ short Ks[2][64 * 64];
    __shared__ short Vs[2][64 * 64];
    const int tid = threadIdx.x;
    const int wave = tid >> 6, lane = tid & 63;
    const int q = lane & 31, hi = lane >> 5;
    // XCD-chunked mapping: all 16 q-tiles of a bh land on one XCD
    const int id = blockIdx.x;                 // 0..1023
    const int bh = (id & 7) * 8 + ((id >> 3) & 7);
    const int qt = id >> 6;                    // 0..15
    const int b = bh >> 4, h = bh & 15;
    const short* Qp = Qg + (size_t)bh * S_SZ * DK;
    const short* Kp = Kg + (size_t)bh * S_SZ * DK;
    const short* Vp = Vtg + (size_t)bh * DK * S_SZ;
    const int q0 = qt * 128 + wave * 32;

    // Q B-fragments (pre-scaled by QSCALE in gemm1): qf[c][e] = Q[q][c*16 + hi*8 + e]
    short8 qf[4];
#pragma unroll
    for (int c = 0; c < 4; ++c)
        qf[c] = *(const short8*)&Qp[(size_t)(q0 + q) * DK + c * 16 + hi * 8];

    f32x16 ot0 = {}, ot1 = {};
    float m_run = -1e30f, l_run = 0.f;

    // staging via global_load_lds: wave w covers rows [w*16, w*16+16) of K and of Vt.
    const int srow0 = wave * 16 + (lane >> 3);
    const int srow1 = srow0 + 8;
    const int sc0 = ((lane & 7) ^ (srow0 & 7)) * 8;   // shorts
    const int sc1 = ((lane & 7) ^ (srow1 & 7)) * 8;
    const short* kg0 = Kp + (size_t)srow0 * DK + sc0;
    const short* kg1 = Kp + (size_t)srow1 * DK + sc1;
    const short* vg0 = Vp + (size_t)srow0 * S_SZ + sc0;
    const short* vg1 = Vp + (size_t)srow1 * S_SZ + sc1;
#define STAGE(BUF)                                                              \
    {                                                                           \
        gld_lds16(kg0, &Ks[BUF][(wave * 16) * 64]);                             \
        gld_lds16(kg1, &Ks[BUF][(wave * 16 + 8) * 64]);                         \
        gld_lds16(vg0, &Vs[BUF][(wave * 16) * 64]);                             \
        gld_lds16(vg1, &Vs[BUF][(wave * 16 + 8) * 64]);                         \
        kg0 += 64 * DK; kg1 += 64 * DK; vg0 += 64; vg1 += 64;                   \
    }

    STAGE(0);

    const int NT = S_SZ / 64;  // 32
    for (int t = 0; t < NT; ++t) {
        __syncthreads();       // drains vmcnt -> tile t staged; syncs prev-buffer readers
        const int cur = t & 1;
        if (t + 1 < NT) STAGE(cur ^ 1);

        // ---- K fragments from LDS (swizzled), ST = K * Q^T ----
        const int qx = (q & 7) << 3;  // swizzle XOR in shorts ((32+q)&7 == q&7)
        f32x16 st0 = {}, st1 = {};
        __builtin_amdgcn_s_setprio(1);
#pragma unroll
        for (int c = 0; c < 4; ++c) {
            const int sw = (((c * 2 + hi) << 3) ^ qx);
            short8 kf0 = *(const short8*)&Ks[cur][q * 64 + sw];
            short8 kf1 = *(const short8*)&Ks[cur][(32 + q) * 64 + sw];
            st0 = __builtin_amdgcn_mfma_f32_32x32x16_bf16(kf0, qf[c], st0, 0, 0, 0);
            st1 = __builtin_amdgcn_mfma_f32_32x32x16_bf16(kf1, qf[c], st1, 0, 0, 0);
        }
        __builtin_amdgcn_s_setprio(0);

        // ---- online softmax in exp2 domain (lane owns col q; kv half per hi) ----
        // max3-shaped reduce: 4 independent chains over 8 values each
        float ma = fmaxf(fmaxf(st0[0], st0[1]), st0[2]);
        float mb = fmaxf(fmaxf(st0[8], st0[9]), st0[10]);
        float mc = fmaxf(fmaxf(st1[0], st1[1]), st1[2]);
        float md = fmaxf(fmaxf(st1[8], st1[9]), st1[10]);
        ma = fmaxf(fmaxf(ma, st0[3]), st0[4]);
        mb = fmaxf(fmaxf(mb, st0[11]), st0[12]);
        mc = fmaxf(fmaxf(mc, st1[3]), st1[4]);
        md = fmaxf(fmaxf(md, st1[11]), st1[12]);
        ma = fmaxf(fmaxf(ma, st0[5]), st0[6]);
        mb = fmaxf(fmaxf(mb, st0[13]), st0[14]);
        mc = fmaxf(fmaxf(mc, st1[5]), st1[6]);
        md = fmaxf(fmaxf(md, st1[13]), st1[14]);
        ma = fmaxf(ma, st0[7]);
        mb = fmaxf(mb, st0[15]);
        mc = fmaxf(mc, st1[7]);
        md = fmaxf(md, st1[15]);
        float pm = fmaxf(fmaxf(ma, mb), fmaxf(mc, md));
        pm = fmaxf(pm, __shfl_xor(pm, 32));
        // defer-max: only rescale when the running max grew by > 8 (=> P <= 2^8)
        if (__any(pm > m_run + 8.f)) {
            float mnew = fmaxf(m_run, pm);
            float corr = EXP2(m_run - mnew);
            m_run = mnew;
            l_run *= corr;
#pragma unroll
            for (int r = 0; r < 16; ++r) { ot0[r] *= corr; ot1[r] *= corr; }
        }
        float s0 = 0.f, s1 = 0.f, s2 = 0.f, s3 = 0.f;
#pragma unroll
        for (int r = 0; r < 16; r += 4) {
            st0[r] = EXP2(st0[r] - m_run);         s0 += st0[r];
            st0[r + 1] = EXP2(st0[r + 1] - m_run); s1 += st0[r + 1];
            st0[r + 2] = EXP2(st0[r + 2] - m_run); s2 += st0[r + 2];
            st0[r + 3] = EXP2(st0[r + 3] - m_run); s3 += st0[r + 3];
        }
#pragma unroll
        for (int r = 0; r < 16; r += 4) {
            st1[r] = EXP2(st1[r] - m_run);         s0 += st1[r];
            st1[r + 1] = EXP2(st1[r + 1] - m_run); s1 += st1[r + 1];
            st1[r + 2] = EXP2(st1[r + 2] - m_run); s2 += st1[r + 2];
            st1[r + 3] = EXP2(st1[r + 3] - m_run); s3 += st1[r + 3];
        }
        float ssum = (s0 + s1) + (s2 + s3);
        ssum += __shfl_xor(ssum, 32);
        l_run += ssum;

        // ---- PV: build P B-frags (cvt_pk + permlane32_swap), OT += Vt * P ----
        __builtin_amdgcn_s_setprio(1);
#if __has_builtin(__builtin_amdgcn_permlane32_swap)
#define PVCHUNK(ST, B0, CH)                                                    \
    {                                                                          \
        uint32_t A01 = pk2f(ST[(B0) + 0], ST[(B0) + 1]);                       \
        uint32_t A23 = pk2f(ST[(B0) + 2], ST[(B0) + 3]);                       \
        uint32_t B45 = pk2f(ST[(B0) + 4], ST[(B0) + 5]);                       \
        uint32_t B67 = pk2f(ST[(B0) + 6], ST[(B0) + 7]);                       \
        auto sw0 = __builtin_amdgcn_permlane32_swap(A01, B45, false, false);   \
        auto sw1 = __builtin_amdgcn_permlane32_swap(A23, B67, false, false);   \
        union { uint32_t u[4]; short8 s8; } pbu;                               \
        pbu.u[0] = sw0[0]; pbu.u[1] = sw1[0];                                  \
        pbu.u[2] = sw0[1]; pbu.u[3] = sw1[1];                                  \
        const int vsw = ((((CH) * 2 + hi) << 3) ^ qx);                         \
        short8 vf0 = *(const short8*)&Vs[cur][q * 64 + vsw];                   \
        short8 vf1 = *(const short8*)&Vs[cur][(32 + q) * 64 + vsw];            \
        ot0 = __builtin_amdgcn_mfma_f32_32x32x16_bf16(vf0, pbu.s8, ot0, 0, 0, 0); \
        ot1 = __builtin_amdgcn_mfma_f32_32x32x16_bf16(vf1, pbu.s8, ot1, 0, 0, 0); \
    }
#else
#define PVCHUNK(ST, B0, CH)                                                    \
    {                                                                          \
        uint32_t A01 = pk2f(ST[(B0) + 0], ST[(B0) + 1]);                       \
        uint32_t A23 = pk2f(ST[(B0) + 2], ST[(B0) + 3]);                       \
        uint32_t B45 = pk2f(ST[(B0) + 4], ST[(B0) + 5]);                       \
        uint32_t B67 = pk2f(ST[(B0) + 6], ST[(B0) + 7]);                       \
        uint32_t t0 = hi ? A01 : B45, t1 = hi ? A23 : B67;                     \
        uint32_t r0 = (uint32_t)__shfl_xor((int)t0, 32);                       \
        uint32_t r1 = (uint32_t)__shfl_xor((int)t1, 32);                       \
        union { uint32_t u[4]; short8 s8; } pbu;                               \
        pbu.u[0] = hi ? r0 : A01; pbu.u[1] = hi ? r1 : A23;                    \
        pbu.u[2] = hi ? B45 : r0; pbu.u[3] = hi ? B67 : r1;                    \
        const int vsw = ((((CH) * 2 + hi) << 3) ^ qx);                         \
        short8 vf0 = *(const short8*)&Vs[cur][q * 64 + vsw];                   \
        short8 vf1 = *(const short8*)&Vs[cur][(32 + q) * 64 + vsw];            \
        ot0 = __builtin_amdgcn_mfma_f32_32x32x16_bf16(vf0, pbu.s8, ot0, 0, 0, 0); \
        ot1 = __builtin_amdgcn_mfma_f32_32x32x16_bf16(vf1, pbu.s8, ot1, 0, 0, 0); \
    }
#endif
        PVCHUNK(st0, 0, 0);
        PVCHUNK(st0, 8, 1);
        PVCHUNK(st1, 0, 2);
        PVCHUNK(st1, 8, 3);
#undef PVCHUNK
        __builtin_amdgcn_s_setprio(0);
    }
#undef STAGE

    // ---- epilogue: O[b][s][h*64+d] = OT[d][q] / l ----
    float inv = 1.f / l_run;
    size_t rowbase = ((size_t)b * S_SZ + (q0 + q)) * MODEL + h * DK;
#pragma unroll
    for (int i = 0; i < 4; ++i) {
        short4v v0, v1;
#pragma unroll
        for (int jj = 0; jj < 4; ++jj) {
            v0[jj] = f2bf(ot0[4 * i + jj] * inv);
            v1[jj] = f2bf(ot1[4 * i + jj] * inv);
        }
        *(short4v*)&O[rowbase + 8 * i + 4 * hi] = v0;
        *(short4v*)&O[rowbase + 32 + 8 * i + 4 * hi] = v1;
    }
}

extern "C" void kernel_launch(void* const* d_in, const int* in_sizes, int n_in,
                              void* d_out, int out_size, void* d_ws, size_t ws_size,
                              hipStream_t stream) {
    const float* x    = (const float*)d_in[0];
    const float* Wqkv = (const float*)d_in[1];
    const float* bqkv = (const float*)d_in[2];
    const float* Wo   = (const float*)d_in[3];
    const float* bo   = (const float*)d_in[4];
    float* out = (float*)d_out;
    char* ws = (char*)d_ws;

    short* xb  = (short*)(ws + 0);           // 16 MiB
    short* wqb = (short*)(ws + 16777216);    //  6 MiB
    short* wob = (short*)(ws + 23068672);    //  2 MiB
    short* Qb  = (short*)(ws + 25165824);    // 16 MiB
    short* Kb  = (short*)(ws + 41943040);    // 16 MiB
    short* Vt  = (short*)(ws + 58720256);    // 16 MiB (transposed [bh][d][s])
    short* Ob  = (short*)(ws + 0);           // aliases xb (dead after gemm1)

    cvt_kernel<<<dim3(2048), dim3(256), 0, stream>>>(x, Wqkv, Wo, xb, wqb, wob);
    gemm_bt<0><<<dim3(QKV_DIM / 128, M_ROWS / 128), dim3(256), 0, stream>>>(
        xb, wqb, bqkv, nullptr, Qb, Kb, Vt, M_ROWS, QKV_DIM, IN_DIM);
    attn_kernel<<<dim3(1024), dim3(256), 0, stream>>>(Qb, Kb, Vt, Ob);
    gemm_bt<1><<<dim3(MODEL / 128, M_ROWS / 128), dim3(256), 0, stream>>>(
        Ob, wob, bo, out, nullptr, nullptr, nullptr, M_ROWS, MODEL, IN_DIM);
}